// Round 8
// baseline (48.370 us; speedup 1.0000x reference)
//
#include <hip/hip_runtime.h>
#include <math.h>

#define N9     6000
#define N10    9000
#define FDIM   128
#define ALPHA  0.2f
#define MAXNBR 64
#define MAXREG 8                       // fast-path register-resident neighbors
#define WPB    4                       // waves per 256-thread block
#define GRID   ((N10 + WPB - 1) / WPB) // 2250 blocks -> 9000 waves, covers both versions

typedef float f32x4 __attribute__((ext_vector_type(4)));

// Butterfly sum: every lane ends up holding the wave-wide total.
__device__ __forceinline__ float wave_bcast_sum(float x) {
    #pragma unroll
    for (int o = 32; o > 0; o >>= 1) x += __shfl_xor(x, o);
    return x;
}

// ---------------------------------------------------------------------------
// Wave-per-row fused GAT. Each 64-lane wave owns one query row end-to-end:
//   S0: load Q[i] (2 floats/lane), qa1/qa2 via butterfly reduce.
//   S1: scan the adjacency row (f32x4, 4-deep); push nonzero column indices
//       into this wave's LDS list. At 2 wave-uniform checkpoints (+ drain),
//       issue K-row loads for newly-found neighbors into NAMED registers —
//       the waitcnt lands at first use (after the scan), so gather latency
//       hides under the remaining scan instead of piling up at the end.
//   S2 fast (cnt<=8): dots/softmax/accumulate from the prefetched registers
//       (K read exactly once, mostly pre-loaded).
//   S2 slow (cnt>8, rare): serial per-neighbor path via LDS.
// No __syncthreads in the row loop; intra-wave LDS visibility via
// __threadfence_block().
// ---------------------------------------------------------------------------
__global__ __launch_bounds__(256)
void gat_wave_kernel(const int* __restrict__ version,
                     const float* __restrict__ U9,
                     const float* __restrict__ U10,
                     const float* __restrict__ a,
                     const float* __restrict__ adj9to10,
                     const float* __restrict__ adj10to9,
                     float* __restrict__ out) {
    const int v  = version[0];
    const int nq = v ? N10 : N9;
    const int nk = v ? N9  : N10;
    const float* __restrict__ Q      = v ? U10 : U9;
    const float* __restrict__ K      = v ? U9  : U10;
    const float* __restrict__ adjmat = v ? adj10to9 : adj9to10;

    __shared__ float s_a1[FDIM], s_a2[FDIM];
    __shared__ int   s_j[WPB][MAXNBR];
    __shared__ float s_e[WPB][MAXNBR];
    __shared__ int   s_cnt[WPB];

    const int t    = threadIdx.x;
    const int wave = t >> 6;
    const int lane = t & 63;

    if (t < FDIM) { s_a1[t] = a[t]; s_a2[t] = a[FDIM + t]; }
    __syncthreads();  // once, outside the row loop

    const float a1lo = s_a1[lane], a1hi = s_a1[lane + 64];
    const float a2lo = s_a2[lane], a2hi = s_a2[lane + 64];

    const int gw = blockIdx.x * WPB + wave;
    const int nw = gridDim.x * WPB;
    const int n4 = nk >> 2;

    for (int i = gw; i < nq; i += nw) {
        if (lane == 0) s_cnt[wave] = 0;  // wave-local; ordered before atomics

        // S0: query row + dots
        const float* qr = Q + (size_t)i * FDIM;
        float qx0 = qr[lane], qx1 = qr[lane + 64];
        float qa1 = wave_bcast_sum(qx0 * a1lo + qx1 * a1hi);
        float qa2 = wave_bcast_sum(qx0 * a2lo + qx1 * a2hi);

        // Prefetched neighbor rows (named regs -> no scratch, waitcnt at use).
        float kA0=0.f,kA1=0.f,kA2=0.f,kA3=0.f,kA4=0.f,kA5=0.f,kA6=0.f,kA7=0.f;
        float kB0=0.f,kB1=0.f,kB2=0.f,kB3=0.f,kB4=0.f,kB5=0.f,kB6=0.f,kB7=0.f;
        int done = 0;

        #define PREF_DRAIN(limit_expr)                                         \
        {                                                                      \
            __threadfence_block();                                             \
            int c_now = s_cnt[wave];                                           \
            if (c_now > (limit_expr)) c_now = (limit_expr);                    \
            while (done < c_now) {                                             \
                const int j = s_j[wave][done];                                 \
                const float* kr = K + (size_t)j * FDIM;                        \
                float lo = kr[lane], hi = kr[lane + 64];                       \
                switch (done) {                                                \
                    case 0: kA0 = lo; kB0 = hi; break;                         \
                    case 1: kA1 = lo; kB1 = hi; break;                         \
                    case 2: kA2 = lo; kB2 = hi; break;                         \
                    case 3: kA3 = lo; kB3 = hi; break;                         \
                    case 4: kA4 = lo; kB4 = hi; break;                         \
                    case 5: kA5 = lo; kB5 = hi; break;                         \
                    case 6: kA6 = lo; kB6 = hi; break;                         \
                    default: kA7 = lo; kB7 = hi; break;                        \
                }                                                              \
                ++done;                                                        \
            }                                                                  \
        }

        // S1: adjacency scan, 4 loads in flight per lane
        const f32x4* __restrict__ adj4 = (const f32x4*)(adjmat + (size_t)i * nk);
        int g = 0;
        for (int p0 = lane; p0 < n4; p0 += 64 * 4, ++g) {
            const int p1 = p0 + 64, p2 = p0 + 128, p3 = p0 + 192;
            f32x4 r0 = adj4[p0];
            f32x4 r1 = (f32x4)(0.f), r2 = (f32x4)(0.f), r3 = (f32x4)(0.f);
            if (p1 < n4) r1 = adj4[p1];
            if (p2 < n4) r2 = adj4[p2];
            if (p3 < n4) r3 = adj4[p3];

            f32x4 rr[4] = {r0, r1, r2, r3};
            int   pp[4] = {p0, p1, p2, p3};
            #pragma unroll
            for (int u = 0; u < 4; ++u) {
                f32x4 vv = rr[u];
                if (vv.x > 0.f || vv.y > 0.f || vv.z > 0.f || vv.w > 0.f) {
                    float va[4] = {vv.x, vv.y, vv.z, vv.w};
                    #pragma unroll
                    for (int c = 0; c < 4; ++c) {
                        if (va[c] > 0.f) {
                            int idx = atomicAdd(&s_cnt[wave], 1);
                            if (idx < MAXNBR) s_j[wave][idx] = pp[u] * 4 + c;
                        }
                    }
                }
            }

            // mid-scan prefetch checkpoints (wave-uniform)
            if (g == 2 || g == 5) PREF_DRAIN(MAXREG);
        }
        // final drain: issue any remaining neighbor loads
        PREF_DRAIN(MAXREG);

        int cnt = s_cnt[wave];
        if (cnt > MAXNBR) cnt = MAXNBR;

        // self score (needed by both paths)
        float se = qa1 + qa2;
        se = (se >= 0.f) ? se : ALPHA * se;

        float h0, h1;
        if (cnt <= MAXREG) {
            // ---- fast path: dots/softmax/accumulate from prefetched regs ----
            float e[MAXREG];
            float m = se;
            #define DOT_STEP(c, KA, KB)                                        \
            if (c < cnt) {                                                     \
                float d  = wave_bcast_sum(KA * a2lo + KB * a2hi);              \
                float ee = qa1 + d;                                            \
                ee = (ee >= 0.f) ? ee : ALPHA * ee;                            \
                e[c] = ee;                                                     \
                m = fmaxf(m, ee);                                              \
            }
            DOT_STEP(0, kA0, kB0) DOT_STEP(1, kA1, kB1)
            DOT_STEP(2, kA2, kB2) DOT_STEP(3, kA3, kB3)
            DOT_STEP(4, kA4, kB4) DOT_STEP(5, kA5, kB5)
            DOT_STEP(6, kA6, kB6) DOT_STEP(7, kA7, kB7)
            #undef DOT_STEP

            float wself = __expf(se - m);
            float wsum  = wself;
            float w[MAXREG];
            #pragma unroll
            for (int c = 0; c < MAXREG; ++c) {
                if (c < cnt) { w[c] = __expf(e[c] - m); wsum += w[c]; }
            }
            const float inv = 1.f / wsum;
            h0 = wself * inv * qx0;
            h1 = wself * inv * qx1;
            #define ACC_STEP(c, KA, KB)                                        \
            if (c < cnt) { const float wc = w[c] * inv; h0 += wc * KA; h1 += wc * KB; }
            ACC_STEP(0, kA0, kB0) ACC_STEP(1, kA1, kB1)
            ACC_STEP(2, kA2, kB2) ACC_STEP(3, kA3, kB3)
            ACC_STEP(4, kA4, kB4) ACC_STEP(5, kA5, kB5)
            ACC_STEP(6, kA6, kB6) ACC_STEP(7, kA7, kB7)
            #undef ACC_STEP
        } else {
            // ---- slow path (rare): serial per-neighbor via LDS ----
            for (int c = 0; c < cnt; ++c) {
                const int j = s_j[wave][c];
                const float* kr = K + (size_t)j * FDIM;
                float d = wave_bcast_sum(kr[lane] * a2lo + kr[lane + 64] * a2hi);
                float ee = qa1 + d;
                if (lane == 0) s_e[wave][c] = (ee >= 0.f) ? ee : ALPHA * ee;
            }
            __threadfence_block();
            float m = se;
            for (int c = 0; c < cnt; ++c) m = fmaxf(m, s_e[wave][c]);
            float wself = __expf(se - m);
            float wsum  = wself;
            for (int c = 0; c < cnt; ++c) wsum += __expf(s_e[wave][c] - m);
            const float inv = 1.f / wsum;
            h0 = wself * inv * qx0;
            h1 = wself * inv * qx1;
            for (int c = 0; c < cnt; ++c) {
                const int j = s_j[wave][c];
                const float wc = __expf(s_e[wave][c] - m) * inv;
                const float* kr = K + (size_t)j * FDIM;
                h0 += wc * kr[lane];
                h1 += wc * kr[lane + 64];
            }
        }
        #undef PREF_DRAIN

        h0 = (h0 > 0.f) ? h0 : expm1f(h0);
        h1 = (h1 > 0.f) ? h1 : expm1f(h1);
        out[(size_t)i * FDIM + lane]      = h0;
        out[(size_t)i * FDIM + lane + 64] = h1;
    }
}

extern "C" void kernel_launch(void* const* d_in, const int* in_sizes, int n_in,
                              void* d_out, int out_size, void* d_ws, size_t ws_size,
                              hipStream_t stream) {
    const int*   d_version = (const int*)d_in[0];
    const float* d_U9      = (const float*)d_in[1];
    const float* d_U10     = (const float*)d_in[2];
    const float* d_a       = (const float*)d_in[3];
    const float* d_adj9    = (const float*)d_in[4];
    const float* d_adj10   = (const float*)d_in[5];
    float*       d_o       = (float*)d_out;

    gat_wave_kernel<<<GRID, 256, 0, stream>>>(
        d_version, d_U9, d_U10, d_a, d_adj9, d_adj10, d_o);
}

// Round 9
// 44.980 us; speedup vs baseline: 1.0754x; 1.0754x over previous
//
#include <hip/hip_runtime.h>
#include <math.h>

#define N9     6000
#define N10    9000
#define FDIM   128
#define ALPHA  0.2f
#define MAXNBR 64
#define MAXREG 8                       // fast-path register-resident neighbors
#define WPB    4                       // waves per 256-thread block
#define GRID   ((N10 + WPB - 1) / WPB) // 2250 blocks -> 9000 waves, covers both versions

typedef float f32x4 __attribute__((ext_vector_type(4)));
typedef int   i32x4 __attribute__((ext_vector_type(4)));

// Butterfly sum: every lane ends up holding the wave-wide total.
__device__ __forceinline__ float wave_bcast_sum(float x) {
    #pragma unroll
    for (int o = 32; o > 0; o >>= 1) x += __shfl_xor(x, o);
    return x;
}

// ---------------------------------------------------------------------------
// Wave-per-row fused GAT (round-6 structure, streamlined scan).
//   S0: load Q[i] (2 floats/lane), qa1/qa2 via butterfly reduce.
//   S1: scan the adjacency row. Main loop: 8 UNCONDITIONAL f32x4 loads per
//       lane per group (full groups only -> no predication, one issue burst);
//       nonzero test is an integer OR (values are exactly 0.0f/1.0f).
//       Tail loop handles the remainder. Found columns -> wave's LDS list.
//   S2 fast (cnt<=8): batch-load all neighbor rows into static register
//       arrays, ILP'd dot reduces, in-register softmax, accumulate from the
//       same registers (each K row read exactly once).
//   S2 slow (cnt>8, rare): serial per-neighbor path via LDS.
// No __syncthreads in the row loop; intra-wave LDS visibility via
// __threadfence_block().
// ---------------------------------------------------------------------------
__global__ __launch_bounds__(256)
void gat_wave_kernel(const int* __restrict__ version,
                     const float* __restrict__ U9,
                     const float* __restrict__ U10,
                     const float* __restrict__ a,
                     const float* __restrict__ adj9to10,
                     const float* __restrict__ adj10to9,
                     float* __restrict__ out) {
    const int v  = version[0];
    const int nq = v ? N10 : N9;
    const int nk = v ? N9  : N10;
    const float* __restrict__ Q      = v ? U10 : U9;
    const float* __restrict__ K      = v ? U9  : U10;
    const float* __restrict__ adjmat = v ? adj10to9 : adj9to10;

    __shared__ float s_a1[FDIM], s_a2[FDIM];
    __shared__ int   s_j[WPB][MAXNBR];
    __shared__ float s_e[WPB][MAXNBR];
    __shared__ int   s_cnt[WPB];

    const int t    = threadIdx.x;
    const int wave = t >> 6;
    const int lane = t & 63;

    if (t < FDIM) { s_a1[t] = a[t]; s_a2[t] = a[FDIM + t]; }
    __syncthreads();  // once, outside the row loop

    const float a1lo = s_a1[lane], a1hi = s_a1[lane + 64];
    const float a2lo = s_a2[lane], a2hi = s_a2[lane + 64];

    const int gw = blockIdx.x * WPB + wave;
    const int nw = gridDim.x * WPB;
    const int n4 = nk >> 2;          // f32x4 elements per row
    const int nfull = n4 >> 9;       // full groups of 512 f32x4 (8 per lane)

    // Nonzero test via integer OR (adj values are exactly 0.0f or 1.0f),
    // then per-element float test for the (rare) hit.
    #define PROCESS(vv, pidx)                                                  \
    {                                                                          \
        i32x4 _u = __builtin_bit_cast(i32x4, (vv));                            \
        if ((_u.x | _u.y | _u.z | _u.w) != 0) {                                \
            const int _b = (pidx) * 4;                                         \
            if ((vv).x > 0.f) { int _i = atomicAdd(&s_cnt[wave], 1);           \
                if (_i < MAXNBR) s_j[wave][_i] = _b;     }                     \
            if ((vv).y > 0.f) { int _i = atomicAdd(&s_cnt[wave], 1);           \
                if (_i < MAXNBR) s_j[wave][_i] = _b + 1; }                     \
            if ((vv).z > 0.f) { int _i = atomicAdd(&s_cnt[wave], 1);           \
                if (_i < MAXNBR) s_j[wave][_i] = _b + 2; }                     \
            if ((vv).w > 0.f) { int _i = atomicAdd(&s_cnt[wave], 1);           \
                if (_i < MAXNBR) s_j[wave][_i] = _b + 3; }                     \
        }                                                                      \
    }

    for (int i = gw; i < nq; i += nw) {
        if (lane == 0) s_cnt[wave] = 0;  // wave-local; ordered before atomics

        // S0: query row + dots
        const float* qr = Q + (size_t)i * FDIM;
        float qx0 = qr[lane], qx1 = qr[lane + 64];
        float qa1 = wave_bcast_sum(qx0 * a1lo + qx1 * a1hi);
        float qa2 = wave_bcast_sum(qx0 * a2lo + qx1 * a2hi);

        // S1a: full groups — 8 unconditional loads per lane, one issue burst.
        const f32x4* __restrict__ adj4 = (const f32x4*)(adjmat + (size_t)i * nk);
        for (int g = 0; g < nfull; ++g) {
            const int base = (g << 9) + lane;
            f32x4 r0 = adj4[base];
            f32x4 r1 = adj4[base + 64];
            f32x4 r2 = adj4[base + 128];
            f32x4 r3 = adj4[base + 192];
            f32x4 r4 = adj4[base + 256];
            f32x4 r5 = adj4[base + 320];
            f32x4 r6 = adj4[base + 384];
            f32x4 r7 = adj4[base + 448];
            PROCESS(r0, base)
            PROCESS(r1, base + 64)
            PROCESS(r2, base + 128)
            PROCESS(r3, base + 192)
            PROCESS(r4, base + 256)
            PROCESS(r5, base + 320)
            PROCESS(r6, base + 384)
            PROCESS(r7, base + 448)
        }
        // S1b: tail
        for (int p = (nfull << 9) + lane; p < n4; p += 64) {
            f32x4 r = adj4[p];
            PROCESS(r, p)
        }
        __threadfence_block();  // s_j/s_cnt visible wave-wide
        int cnt = s_cnt[wave];
        if (cnt > MAXNBR) cnt = MAXNBR;

        // self score (needed by both paths)
        float se = qa1 + qa2;
        se = (se >= 0.f) ? se : ALPHA * se;

        float h0, h1;
        if (cnt <= MAXREG) {
            // ---- fast path: everything register-resident ----
            float k0[MAXREG], k1[MAXREG];
            #pragma unroll
            for (int c = 0; c < MAXREG; ++c) {
                if (c < cnt) {
                    const float* kr = K + (size_t)s_j[wave][c] * FDIM;
                    k0[c] = kr[lane]; k1[c] = kr[lane + 64];  // all issued before use
                }
            }
            float e[MAXREG];
            float m = se;
            #pragma unroll
            for (int c = 0; c < MAXREG; ++c) {
                if (c < cnt) {
                    float d  = wave_bcast_sum(k0[c] * a2lo + k1[c] * a2hi);
                    float ee = qa1 + d;
                    ee = (ee >= 0.f) ? ee : ALPHA * ee;
                    e[c] = ee;
                    m = fmaxf(m, ee);
                }
            }
            float wself = __expf(se - m);
            float wsum  = wself;
            float w[MAXREG];
            #pragma unroll
            for (int c = 0; c < MAXREG; ++c) {
                if (c < cnt) { w[c] = __expf(e[c] - m); wsum += w[c]; }
            }
            const float inv = 1.f / wsum;
            h0 = wself * inv * qx0;
            h1 = wself * inv * qx1;
            #pragma unroll
            for (int c = 0; c < MAXREG; ++c) {
                if (c < cnt) {
                    const float wc = w[c] * inv;
                    h0 += wc * k0[c];
                    h1 += wc * k1[c];
                }
            }
        } else {
            // ---- slow path (rare): serial per-neighbor via LDS ----
            for (int c = 0; c < cnt; ++c) {
                const int j = s_j[wave][c];
                const float* kr = K + (size_t)j * FDIM;
                float d = wave_bcast_sum(kr[lane] * a2lo + kr[lane + 64] * a2hi);
                float ee = qa1 + d;
                if (lane == 0) s_e[wave][c] = (ee >= 0.f) ? ee : ALPHA * ee;
            }
            __threadfence_block();
            float m = se;
            for (int c = 0; c < cnt; ++c) m = fmaxf(m, s_e[wave][c]);
            float wself = __expf(se - m);
            float wsum  = wself;
            for (int c = 0; c < cnt; ++c) wsum += __expf(s_e[wave][c] - m);
            const float inv = 1.f / wsum;
            h0 = wself * inv * qx0;
            h1 = wself * inv * qx1;
            for (int c = 0; c < cnt; ++c) {
                const int j = s_j[wave][c];
                const float wc = __expf(s_e[wave][c] - m) * inv;
                const float* kr = K + (size_t)j * FDIM;
                h0 += wc * kr[lane];
                h1 += wc * kr[lane + 64];
            }
        }

        h0 = (h0 > 0.f) ? h0 : expm1f(h0);
        h1 = (h1 > 0.f) ? h1 : expm1f(h1);
        out[(size_t)i * FDIM + lane]      = h0;
        out[(size_t)i * FDIM + lane + 64] = h1;
    }
    #undef PROCESS
}

extern "C" void kernel_launch(void* const* d_in, const int* in_sizes, int n_in,
                              void* d_out, int out_size, void* d_ws, size_t ws_size,
                              hipStream_t stream) {
    const int*   d_version = (const int*)d_in[0];
    const float* d_U9      = (const float*)d_in[1];
    const float* d_U10     = (const float*)d_in[2];
    const float* d_a       = (const float*)d_in[3];
    const float* d_adj9    = (const float*)d_in[4];
    const float* d_adj10   = (const float*)d_in[5];
    float*       d_o       = (float*)d_out;

    gat_wave_kernel<<<GRID, 256, 0, stream>>>(
        d_version, d_U9, d_U10, d_a, d_adj9, d_adj10, d_o);
}